// Round 8
// baseline (98.143 us; speedup 1.0000x reference)
//
#include <hip/hip_runtime.h>
#include <hip/hip_bf16.h>

// 3x3 VALID conv via bf16 MFMA implicit GEMM.
// x: (64,224,224) fp32, w: (128,64,3,3) fp32, out: (128,222,222) fp32.
//
// R8: conv rebuilt around mfma_f32_32x32x16_bf16 (2x MACs per LDS read).
// R7 analysis: LDS pipe ~9x oversubscribed vs MFMA (530 b128/block, 288 of
// them duplicate A-reads across waves). Changes:
//  - wave tile 64co x 64n (2ms x 2nt of 32x32), 1 b128 read per MFMA
//  - block 64co x 8oh x 32ow (N=256): full 128B-line epilogue stores
//  - A-fragments batched from global (wt is L2-hot, 147KB) into registers
//    per filter row -> zero weight LDS traffic; xs is the only LDS user.
// A layout: m=lane&31, k=(lane>>5)*8+j. B: n=lane&31, same k.
// D: col(n)=lane&31, row(m)=(reg&3)+8*(reg>>2)+4*(lane>>5).

#define H_IN   224
#define W_IN   224
#define C_OUT  128
#define H_OUT  222
#define W_OUT  222
#define XP     226   // padded spatial extent of xt
#define CPAD   72    // padded c stride in conv x-LDS (16B-aligned rows)
#define TW     68    // padded w stride in transpose LDS

typedef __attribute__((ext_vector_type(8)))  short bf16x8;
typedef __attribute__((ext_vector_type(16))) float f32x16;

static __device__ __forceinline__ unsigned short f2bs(float f) {
    union { __hip_bfloat16 h; unsigned short u; } cv;
    cv.h = __float2bfloat16(f);
    return cv.u;
}

__global__ __launch_bounds__(256)
void transform_w_kernel(const float* __restrict__ w, __hip_bfloat16* __restrict__ wt)
{
    int idx = blockIdx.x * 256 + threadIdx.x;     // [ij][co][c], 9*128*64
    if (idx < 9 * 128 * 64) {
        int ij  = idx >> 13;
        int rem = idx & 8191;
        int co  = rem >> 6;
        int c   = rem & 63;
        wt[idx] = __float2bfloat16(w[(co * 64 + c) * 9 + ij]);
    }
}

__global__ __launch_bounds__(256)
void transpose_x_kernel(const float* __restrict__ x, __hip_bfloat16* __restrict__ xt)
{
    __shared__ __align__(16) unsigned short tile[64 * TW];   // [c][w_local]
    const int h  = blockIdx.y;                 // 0..225
    const int w0 = blockIdx.x * 64;            // 0,64,128,192
    const int t  = threadIdx.x;

    // Phase 1: coalesced float4 reads along w; zeros for padded h/w.
    {
        const int wq = (t & 15) * 4;           // 0..60 (lanes contiguous in w)
        const int c0 = t >> 4;                 // 0..15
        #pragma unroll
        for (int p = 0; p < 4; ++p) {
            const int c  = c0 + p * 16;
            const int wg = w0 + wq;
            float4 v = make_float4(0.f, 0.f, 0.f, 0.f);
            if (h < H_IN && wg < W_IN)         // wg%4==0, W_IN%4==0 -> all-or-nothing
                v = *(const float4*)(x + ((size_t)c * H_IN + h) * W_IN + wg);
            ushort4 b;
            b.x = f2bs(v.x); b.y = f2bs(v.y); b.z = f2bs(v.z); b.w = f2bs(v.w);
            *(ushort4*)(tile + c * TW + wq) = b;   // (c*136 + wq*2) % 8 == 0
        }
    }
    __syncthreads();

    // Phase 2: gather 16 c per thread from LDS, contiguous 16B/lane stores.
    {
        const int wl = t >> 2;                 // 0..63
        const int cq = (t & 3) * 16;           // 0,16,32,48
        const int wg = w0 + wl;
        if (wg < XP) {
            alignas(16) unsigned short r[16];
            #pragma unroll
            for (int k = 0; k < 16; ++k)
                r[k] = tile[(cq + k) * TW + wl];
            float4* d = (float4*)((unsigned short*)xt + ((size_t)h * XP + wg) * 64 + cq);
            d[0] = ((const float4*)r)[0];
            d[1] = ((const float4*)r)[1];
        }
    }
}

__global__ __launch_bounds__(256)
void conv_mfma_kernel(const __hip_bfloat16* __restrict__ xt,
                      const __hip_bfloat16* __restrict__ wt,
                      float* __restrict__ out)
{
    __shared__ __hip_bfloat16 xs[10 * 34 * CPAD];   // [row][wc][c]  48,960 B
    const int ow0 = blockIdx.x * 32;
    const int oh0 = blockIdx.y * 8;
    const int co0 = blockIdx.z * 64;
    const int tid = threadIdx.x;

    // Stage x tile: rows oh0..oh0+9, cols ow0..ow0+33, all 64 c (bf16).
    for (int q = tid; q < 10 * 34 * 8; q += 256) {
        int sub = q & 7;
        int pix = q >> 3;
        int row = pix / 34;
        int wc  = pix - row * 34;
        *(float4*)(xs + (row * 34 + wc) * CPAD + sub * 8) =
            *(const float4*)(xt + ((oh0 + row) * XP + (ow0 + wc)) * 64 + sub * 8);
    }
    __syncthreads();

    const int wave = tid >> 6;
    const int lane = tid & 63;
    const int n    = lane & 31;     // A: co offset; B: ow offset; D: col
    const int h    = lane >> 5;     // k-half selector

    f32x16 acc[2][2] = {};          // [mi][ni]; wave rows oh0+2*wave+ni

    #pragma unroll
    for (int i = 0; i < 3; ++i) {   // filter row
        // Batch-load this row's A fragments from global (L2-hot wt):
        // 24 independent dwordx4 loads issued before any use.
        bf16x8 afr[3][2][4];        // [tap][mi][kstep]
        #pragma unroll
        for (int jj = 0; jj < 3; ++jj)
            #pragma unroll
            for (int mi = 0; mi < 2; ++mi)
                #pragma unroll
                for (int t = 0; t < 4; ++t)
                    afr[jj][mi][t] = *(const bf16x8*)(wt +
                        ((i * 3 + jj) * 128 + co0 + mi * 32 + n) * 64 + t * 16 + h * 8);

        #pragma unroll
        for (int jj = 0; jj < 3; ++jj) {
            #pragma unroll
            for (int t = 0; t < 4; ++t) {
                bf16x8 bfr[2];
                #pragma unroll
                for (int ni = 0; ni < 2; ++ni)
                    bfr[ni] = *(const bf16x8*)(xs +
                        ((wave * 2 + ni + i) * 34 + n + jj) * CPAD + t * 16 + h * 8);
                #pragma unroll
                for (int mi = 0; mi < 2; ++mi)
                    #pragma unroll
                    for (int ni = 0; ni < 2; ++ni)
                        acc[mi][ni] = __builtin_amdgcn_mfma_f32_32x32x16_bf16(
                            afr[jj][mi][t], bfr[ni], acc[mi][ni], 0, 0, 0);
            }
        }
    }

    // Epilogue: lanes 0..31 = 32 consecutive ow -> 128B full-line stores.
    #pragma unroll
    for (int mi = 0; mi < 2; ++mi) {
        #pragma unroll
        for (int ni = 0; ni < 2; ++ni) {
            const int oh = oh0 + wave * 2 + ni;
            const int ow = ow0 + n;
            if (oh < H_OUT && ow < W_OUT) {
                #pragma unroll
                for (int r = 0; r < 16; ++r) {
                    int co = co0 + mi * 32 + (r & 3) + 8 * (r >> 2) + 4 * h;
                    out[(size_t)co * (H_OUT * W_OUT) + oh * W_OUT + ow] = acc[mi][ni][r];
                }
            }
        }
    }
}

extern "C" void kernel_launch(void* const* d_in, const int* in_sizes, int n_in,
                              void* d_out, int out_size, void* d_ws, size_t ws_size,
                              hipStream_t stream)
{
    const float* x = (const float*)d_in[0];
    const float* w = (const float*)d_in[1];
    float* out     = (float*)d_out;

    __hip_bfloat16* xt = (__hip_bfloat16*)d_ws;                      // 226*226*64*2 B
    __hip_bfloat16* wt = (__hip_bfloat16*)((char*)d_ws + (size_t)XP * XP * 64 * 2);

    transform_w_kernel<<<288, 256, 0, stream>>>(w, wt);
    transpose_x_kernel<<<dim3(4, XP), 256, 0, stream>>>(x, xt);
    conv_mfma_kernel<<<dim3(7, 28, 2), 256, 0, stream>>>(xt, wt, out);
}

// Round 9
// 88.077 us; speedup vs baseline: 1.1143x; 1.1143x over previous
//
#include <hip/hip_runtime.h>
#include <hip/hip_bf16.h>

// 3x3 VALID conv via bf16 MFMA implicit GEMM.
// x: (64,224,224) fp32, w: (128,64,3,3) fp32, out: (128,222,222) fp32.
//
// R9: all-LDS 32x32x16 with register-tile reuse (mi=2 x ni=2 -> 1 read per
// 2 MFMAs vs R7's ~0.75/1) and lane-contiguous weight layout
// wt[tap][kstep][co][c8] (A-read = 64 lanes x contiguous 16B = conflict-free
// 1KB LDS transaction). Weights double-buffered per tap (2 x 8KB) so tap p+1
// stages while tap p computes; one barrier per tap. Block 64co x 8oh x 32ow.
// LDS 48,960(xs) + 16,384(ws) = 65,344 B -> 2 blocks/CU.
// A: m=lane&31, k=(lane>>5)*8+j. B: n=lane&31. D: col=lane&31,
// row=(reg&3)+8*(reg>>2)+4*(lane>>5)  [m74/m101-verified].

#define H_IN   224
#define W_IN   224
#define C_OUT  128
#define H_OUT  222
#define W_OUT  222
#define XP     226   // padded spatial extent of xt
#define CPAD   72    // padded c stride in conv x-LDS (144B = 16B*9, bank-floor)
#define TW     68    // padded w stride in transpose LDS

typedef __attribute__((ext_vector_type(8)))  short bf16x8;
typedef __attribute__((ext_vector_type(16))) float f32x16;

static __device__ __forceinline__ unsigned short f2bs(float f) {
    union { __hip_bfloat16 h; unsigned short u; } cv;
    cv.h = __float2bfloat16(f);
    return cv.u;
}

// wt layout: [ij][kstep(=c>>3)][co][c&7]  -> A-fragment reads lane-contiguous.
__global__ __launch_bounds__(256)
void transform_w_kernel(const float* __restrict__ w, __hip_bfloat16* __restrict__ wt)
{
    int idx = blockIdx.x * 256 + threadIdx.x;     // 9*128*64 = 73,728
    if (idx < 9 * 128 * 64) {
        int ij  = idx >> 13;
        int rem = idx & 8191;
        int co  = rem >> 6;
        int c   = rem & 63;
        wt[((ij * 8 + (c >> 3)) * 128 + co) * 8 + (c & 7)] =
            __float2bfloat16(w[(co * 64 + c) * 9 + ij]);
    }
}

__global__ __launch_bounds__(256)
void transpose_x_kernel(const float* __restrict__ x, __hip_bfloat16* __restrict__ xt)
{
    __shared__ __align__(16) unsigned short tile[64 * TW];   // [c][w_local]
    const int h  = blockIdx.y;                 // 0..225
    const int w0 = blockIdx.x * 64;            // 0,64,128,192
    const int t  = threadIdx.x;

    // Phase 1: coalesced float4 reads along w; zeros for padded h/w.
    {
        const int wq = (t & 15) * 4;           // 0..60 (lanes contiguous in w)
        const int c0 = t >> 4;                 // 0..15
        #pragma unroll
        for (int p = 0; p < 4; ++p) {
            const int c  = c0 + p * 16;
            const int wg = w0 + wq;
            float4 v = make_float4(0.f, 0.f, 0.f, 0.f);
            if (h < H_IN && wg < W_IN)         // wg%4==0, W_IN%4==0 -> all-or-nothing
                v = *(const float4*)(x + ((size_t)c * H_IN + h) * W_IN + wg);
            ushort4 b;
            b.x = f2bs(v.x); b.y = f2bs(v.y); b.z = f2bs(v.z); b.w = f2bs(v.w);
            *(ushort4*)(tile + c * TW + wq) = b;   // (c*136 + wq*2) % 8 == 0
        }
    }
    __syncthreads();

    // Phase 2: gather 16 c per thread from LDS, contiguous 16B/lane stores.
    {
        const int wl = t >> 2;                 // 0..63
        const int cq = (t & 3) * 16;           // 0,16,32,48
        const int wg = w0 + wl;
        if (wg < XP) {
            alignas(16) unsigned short r[16];
            #pragma unroll
            for (int k = 0; k < 16; ++k)
                r[k] = tile[(cq + k) * TW + wl];
            float4* d = (float4*)((unsigned short*)xt + ((size_t)h * XP + wg) * 64 + cq);
            d[0] = ((const float4*)r)[0];
            d[1] = ((const float4*)r)[1];
        }
    }
}

__global__ __launch_bounds__(256)
void conv_mfma_kernel(const __hip_bfloat16* __restrict__ xt,
                      const __hip_bfloat16* __restrict__ wt,
                      float* __restrict__ out)
{
    __shared__ __hip_bfloat16 xs[10 * 34 * CPAD];   // [row][wc][c]  48,960 B
    __shared__ __hip_bfloat16 wsb[2][8 * 64 * 8];   // [buf][kstep][co][c8] 2x8,192 B
    const int ow0 = blockIdx.x * 32;
    const int oh0 = blockIdx.y * 8;
    const int co0 = blockIdx.z * 64;
    const int tid = threadIdx.x;

    // Stage x tile: rows oh0..oh0+9, cols ow0..ow0+33, all 64 c (bf16).
    for (int q = tid; q < 10 * 34 * 8; q += 256) {
        int sub = q & 7;
        int pix = q >> 3;
        int row = pix / 34;
        int wc  = pix - row * 34;
        *(float4*)(xs + (row * 34 + wc) * CPAD + sub * 8) =
            *(const float4*)(xt + ((oh0 + row) * XP + (ow0 + wc)) * 64 + sub * 8);
    }
    // Stage tap 0 weights (this block's 64 co): 8,192 B, lane-contiguous.
    {
        const float4* s = (const float4*)(wt + (size_t)co0 * 8);  // kstep-major, co0 strip
        // tap p strip: 8 ksteps x 64 co x 8c; global co-dim is 128 wide.
        #pragma unroll
        for (int k = 0; k < 2; ++k) {
            int q  = k * 256 + tid;          // 512 chunks of 16B
            int ks = q >> 6;                 // kstep 0..7
            int cc = q & 63;                 // co 0..63
            *(float4*)(&wsb[0][(ks * 64 + cc) * 8]) =
                *(const float4*)(wt + ((0 * 8 + ks) * 128 + co0 + cc) * 8);
        }
        (void)s;
    }
    __syncthreads();

    const int wave = tid >> 6;
    const int lane = tid & 63;
    const int n    = lane & 31;     // A: co offset; B: ow offset; D: col
    const int h    = lane >> 5;     // k-half selector
    const int r0   = wave * 2;      // this wave's 2 output rows

    f32x16 acc[2][2] = {};          // [mi][ni]

    #pragma unroll
    for (int p = 0; p < 9; ++p) {   // tap index = i*3 + jj
        const int i  = p / 3;
        const int jj = p - i * 3;
        const int cb = p & 1;

        // Prefetch next tap into the other buffer (before compute; the LDS
        // writes land before the barrier, global latency hidden by compute).
        float4 pf[2];
        int ks0 = 0, cc0 = 0, ks1 = 0, cc1 = 0;
        if (p < 8) {
            #pragma unroll
            for (int k = 0; k < 2; ++k) {
                int q  = k * 256 + tid;
                int ks = q >> 6;
                int cc = q & 63;
                pf[k] = *(const float4*)(wt + (((p + 1) * 8 + ks) * 128 + co0 + cc) * 8);
                if (k == 0) { ks0 = ks; cc0 = cc; } else { ks1 = ks; cc1 = cc; }
            }
        }

        // Compute tap p: 4 k-steps, mi=2 x ni=2 register tile.
        #pragma unroll
        for (int t = 0; t < 4; ++t) {
            bf16x8 afr[2], bfr[2];
            #pragma unroll
            for (int mi = 0; mi < 2; ++mi)
                afr[mi] = *(const bf16x8*)(&wsb[cb][((t * 2 + h) * 64 + mi * 32 + n) * 8]);
            #pragma unroll
            for (int ni = 0; ni < 2; ++ni)
                bfr[ni] = *(const bf16x8*)(xs +
                    ((i + r0 + ni) * 34 + n + jj) * CPAD + t * 16 + h * 8);
            #pragma unroll
            for (int mi = 0; mi < 2; ++mi)
                #pragma unroll
                for (int ni = 0; ni < 2; ++ni)
                    acc[mi][ni] = __builtin_amdgcn_mfma_f32_32x32x16_bf16(
                        afr[mi], bfr[ni], acc[mi][ni], 0, 0, 0);
        }

        if (p < 8) {
            *(float4*)(&wsb[1 - cb][(ks0 * 64 + cc0) * 8]) = pf[0];
            *(float4*)(&wsb[1 - cb][(ks1 * 64 + cc1) * 8]) = pf[1];
        }
        __syncthreads();   // next iter reads wsb[1-cb]; iter after overwrites wsb[cb]
    }

    // Epilogue: lanes 0..31 = 32 consecutive ow -> 128B full-line stores.
    #pragma unroll
    for (int mi = 0; mi < 2; ++mi) {
        #pragma unroll
        for (int ni = 0; ni < 2; ++ni) {
            const int oh = oh0 + r0 + ni;
            const int ow = ow0 + n;
            if (oh < H_OUT && ow < W_OUT) {
                #pragma unroll
                for (int r = 0; r < 16; ++r) {
                    int co = co0 + mi * 32 + (r & 3) + 8 * (r >> 2) + 4 * h;
                    out[(size_t)co * (H_OUT * W_OUT) + oh * W_OUT + ow] = acc[mi][ni][r];
                }
            }
        }
    }
}

extern "C" void kernel_launch(void* const* d_in, const int* in_sizes, int n_in,
                              void* d_out, int out_size, void* d_ws, size_t ws_size,
                              hipStream_t stream)
{
    const float* x = (const float*)d_in[0];
    const float* w = (const float*)d_in[1];
    float* out     = (float*)d_out;

    __hip_bfloat16* xt = (__hip_bfloat16*)d_ws;                      // 226*226*64*2 B
    __hip_bfloat16* wt = (__hip_bfloat16*)((char*)d_ws + (size_t)XP * XP * 64 * 2);

    transform_w_kernel<<<288, 256, 0, stream>>>(w, wt);
    transpose_x_kernel<<<dim3(4, XP), 256, 0, stream>>>(x, xt);
    conv_mfma_kernel<<<dim3(7, 28, 2), 256, 0, stream>>>(xt, wt, out);
}